// Round 14
// baseline (51.810 us; speedup 1.0000x reference)
//
#include <hip/hip_runtime.h>
#include <hip/hip_bf16.h>

typedef short bf16x8 __attribute__((ext_vector_type(8)));
typedef short bf16x4 __attribute__((ext_vector_type(4)));
typedef float f32x4  __attribute__((ext_vector_type(4)));
typedef float f32x16 __attribute__((ext_vector_type(16)));

#define D_DIM 64
#define SEQ 2048
#define BHD (SEQ * D_DIM)
#define SCALE_L2E 0.1803368801111204f   // (1/8) * log2(e)

__device__ __forceinline__ unsigned short f2bf(float f) {
    unsigned u = __builtin_bit_cast(unsigned, f);
    u += 0x7fffu + ((u >> 16) & 1u);
    return (unsigned short)(u >> 16);
}
// XOR-swizzle for row-major [R][64] bf16 tiles (row stride 128B) — T2
__device__ __forceinline__ unsigned swz(unsigned row, unsigned colByte) {
    return (row * 128u + colByte) ^ ((row & 7u) << 4);
}
__device__ __forceinline__ void gl_lds(const unsigned short* g, unsigned char* lds_generic,
                                       unsigned lds_off) {
    __builtin_amdgcn_global_load_lds(
        (const __attribute__((address_space(1))) void*)g,
        (__attribute__((address_space(3))) void*)(lds_generic + lds_off), 16, 0, 0);
}
__device__ __forceinline__ float fexp2(float x) {
    float r; asm("v_exp_f32 %0, %1" : "=v"(r) : "v"(x)); return r;
}
__device__ __forceinline__ unsigned cvtpk(float lo, float hi) {
    unsigned r; asm("v_cvt_pk_bf16_f32 %0, %1, %2" : "=v"(r) : "v"(lo), "v"(hi)); return r;
}

// ---------------- fused prepass: K fp32->bf16, V fp32 [s][d] -> Vt bf16 [d][s] ----------------
__global__ __launch_bounds__(256) void prep_kernel(const float* __restrict__ K,
                                                   const float* __restrict__ V,
                                                   unsigned short* __restrict__ Kb,
                                                   unsigned short* __restrict__ Vt) {
    __shared__ unsigned short t[64][66];
    const int st = blockIdx.x;
    const int bh = blockIdx.y;
    const int tid = threadIdx.x;
    const size_t base = (size_t)bh * BHD;

    const float* ksrc = K + base + st * 4096;
    unsigned short* kdst = Kb + base + st * 4096;
    #pragma unroll
    for (int j = 0; j < 2; ++j) {
        int e = (j * 256 + tid) * 8;
        float4 a = *(const float4*)(ksrc + e);
        float4 b = *(const float4*)(ksrc + e + 4);
        bf16x8 o;
        o[0] = (short)f2bf(a.x); o[1] = (short)f2bf(a.y);
        o[2] = (short)f2bf(a.z); o[3] = (short)f2bf(a.w);
        o[4] = (short)f2bf(b.x); o[5] = (short)f2bf(b.y);
        o[6] = (short)f2bf(b.z); o[7] = (short)f2bf(b.w);
        *(bf16x8*)(kdst + e) = o;
    }

    const float* vb = V + base + st * 64 * D_DIM;
    #pragma unroll
    for (int j = 0; j < 4; ++j) {
        int n = tid + 256 * j;
        int r = n >> 4;
        int c = (n & 15) << 2;
        float4 v = *(const float4*)(vb + r * D_DIM + c);
        t[r][c + 0] = f2bf(v.x); t[r][c + 1] = f2bf(v.y);
        t[r][c + 2] = f2bf(v.z); t[r][c + 3] = f2bf(v.w);
    }
    __syncthreads();
    #pragma unroll
    for (int j = 0; j < 2; ++j) {
        int m = tid + 256 * j;
        int d = m >> 3;
        int s8 = (m & 7) << 3;
        bf16x8 o;
        #pragma unroll
        for (int e = 0; e < 8; ++e) o[e] = (short)t[s8 + e][d];
        *(bf16x8*)(Vt + base + (size_t)d * SEQ + st * 64 + s8) = o;
    }
}

// ---------------- main: constant-length pair blocks (round-13 body verbatim) ----------------
// Block = (bh, pair (i, 31-i) of 64-row q-tiles), processed sequentially.
// 256 thr = 4 waves: rg = w&1 (32-row group), par = w>>1 (kv parity).
// Every block runs exactly 17 staging iterations -> all 512 blocks (2/CU) finish together.
__global__ __launch_bounds__(256, 2) void attn_pair(const float* __restrict__ Qp,
                                                    const unsigned short* __restrict__ Kb,
                                                    const unsigned short* __restrict__ Vtb,
                                                    float* __restrict__ Op) {
    __shared__ __align__(16) unsigned char lds[65536];  // 2 bufs x (K0|V0|K1|V1) 8KB each

    const int id = blockIdx.x;            // 0..511; id&7 = XCD
    const int j  = id >> 3;
    const int bh = (id & 7) * 4 + (j >> 4);
    const int i  = j & 15;                // pair (i, 31-i)

    const int tid  = threadIdx.x;
    const int w    = tid >> 6;            // 0..3
    const int lane = tid & 63;
    const int l31  = lane & 31;
    const int hi2  = lane >> 5;
    const int rg   = w & 1;               // row group (32 rows)
    const int par  = w >> 1;              // kv parity

    const size_t base = (size_t)bh * BHD;
    const float* qp = Qp + base;
    const unsigned short* kb = Kb + base;
    const unsigned short* vt = Vtb + base;
    float* op = Op + base;

    // staging geometry: 8KB image = 2 chunks x (256 thr x 16B); inverse-swizzled source
    int kOff[2], vOff[2];
    #pragma unroll
    for (int h = 0; h < 2; ++h) {
        int Lb = h * 4096 + tid * 16;
        int row = Lb >> 7;
        int cb  = (Lb & 127) ^ ((row & 7) << 4);
        kOff[h] = row * D_DIM + (cb >> 1);
        vOff[h] = row * SEQ + (cb >> 1);
    }
    auto STAGE = [&](int it) {            // tiles (2it, 2it+1) -> buf it&1
        unsigned bb = (unsigned)(it & 1) * 32768u;
        #pragma unroll
        for (int s = 0; s < 2; ++s) {
            const unsigned short* kg = kb + (size_t)(2 * it + s) * 4096;
            const unsigned short* vg = vt + (size_t)(2 * it + s) * 64;
            #pragma unroll
            for (int h = 0; h < 2; ++h) {
                unsigned d = bb + (unsigned)s * 16384u + (unsigned)h * 4096u
                           + (unsigned)tid * 16u;
                gl_lds(kg + kOff[h], lds, d);
                gl_lds(vg + vOff[h], lds, d + 8192u);
            }
        }
    };

    #pragma unroll 1
    for (int ph = 0; ph < 2; ++ph) {
        const int Q   = ph ? (31 - i) : i;     // 64-row q-tile index 0..31
        const int qlo = Q * 64 + rg * 32;
        const int qg  = qlo + l31;
        const int t_w = Q;                     // last active 64-kv tile
        const int nt  = (Q + 2) >> 1;          // staging iterations

        STAGE(0);

        // Q B-frags for this phase's rows (exp2-domain scale folded)
        bf16x8 qB[4];
        {
            const float* qsrc = qp + (size_t)qg * D_DIM + hi2 * 8;
            #pragma unroll
            for (int dk = 0; dk < 4; ++dk) {
                float4 a = *(const float4*)(qsrc + dk * 16);
                float4 b = *(const float4*)(qsrc + dk * 16 + 4);
                bf16x8 v;
                v[0] = (short)f2bf(a.x * SCALE_L2E); v[1] = (short)f2bf(a.y * SCALE_L2E);
                v[2] = (short)f2bf(a.z * SCALE_L2E); v[3] = (short)f2bf(a.w * SCALE_L2E);
                v[4] = (short)f2bf(b.x * SCALE_L2E); v[5] = (short)f2bf(b.y * SCALE_L2E);
                v[6] = (short)f2bf(b.z * SCALE_L2E); v[7] = (short)f2bf(b.w * SCALE_L2E);
                qB[dk] = v;
            }
        }

        f32x16 acc0 = {}, acc1 = {};
        float m_r = -3.0e38f, l_r = 0.f;

        #pragma unroll 1
        for (int it = 0; it < nt; ++it) {
            asm volatile("s_waitcnt vmcnt(0)" ::: "memory");
            __builtin_amdgcn_s_barrier();
            __builtin_amdgcn_sched_barrier(0);
            if (it + 1 < nt) STAGE(it + 1);

            const int tile = 2 * it + par;
            if (tile <= t_w) {                 // wave-uniform
                const unsigned kbuf = (unsigned)(it & 1) * 32768u + (unsigned)par * 16384u;
                const unsigned vbuf = kbuf + 8192u;

                // ---- QK: St[kv][q], A = K rows, B = Q cols ----
                f32x16 st0 = {}, st1 = {};
                __builtin_amdgcn_s_setprio(1);
                #pragma unroll
                for (int dk = 0; dk < 4; ++dk) {
                    bf16x8 k0 = *(const bf16x8*)&lds[kbuf +
                        swz((unsigned)l31, (unsigned)(dk * 32 + hi2 * 16))];
                    bf16x8 k1 = *(const bf16x8*)&lds[kbuf +
                        swz((unsigned)(32 + l31), (unsigned)(dk * 32 + hi2 * 16))];
                    st0 = __builtin_amdgcn_mfma_f32_32x32x16_bf16(k0, qB[dk], st0, 0, 0, 0);
                    st1 = __builtin_amdgcn_mfma_f32_32x32x16_bf16(k1, qB[dk], st1, 0, 0, 0);
                }
                __builtin_amdgcn_s_setprio(0);

                // ---- causal mask (diagonal tile only) ----
                if (tile == t_w) {
                    #pragma unroll
                    for (int r = 0; r < 16; ++r) {
                        int kvb = tile * 64 + (r & 3) + 8 * (r >> 2) + 4 * hi2;
                        if (kvb > qg)      st0[r] = -3.0e38f;
                        if (kvb + 32 > qg) st1[r] = -3.0e38f;
                    }
                }

                // ---- half-max via max3-shaped triples ----
                float m8[8];
                #pragma unroll
                for (int r = 0; r < 8; ++r)
                    m8[r] = fmaxf(fmaxf(fmaxf(st0[r], st0[r + 8]), st1[r]), st1[r + 8]);
                float mx = fmaxf(fmaxf(fmaxf(m8[0], m8[1]), m8[2]),
                                 fmaxf(fmaxf(m8[3], m8[4]),
                                       fmaxf(fmaxf(m8[5], m8[6]), m8[7])));

                // ---- defer-max (T13): __all over 64 lanes covers both halves ----
                float mn;
                if (__all(mx <= m_r + 8.0f)) {
                    mn = m_r;
                } else {
                    float mfull = fmaxf(mx, __shfl_xor(mx, 32));
                    mn = fmaxf(m_r, mfull);
                    float sc = fexp2(m_r - mn);
                    m_r = mn;
                    l_r *= sc;
                    #pragma unroll
                    for (int r = 0; r < 16; ++r) { acc0[r] *= sc; acc1[r] *= sc; }
                }

                // ---- exp (in place) + sum tree ----
                #pragma unroll
                for (int r = 0; r < 16; ++r) st0[r] = fexp2(st0[r] - mn);
                #pragma unroll
                for (int r = 0; r < 16; ++r) st1[r] = fexp2(st1[r] - mn);
                float s16[16];
                #pragma unroll
                for (int r = 0; r < 16; ++r) s16[r] = st0[r] + st1[r];
                #pragma unroll
                for (int r = 0; r < 8; ++r) s16[r] += s16[r + 8];
                #pragma unroll
                for (int r = 0; r < 4; ++r) s16[r] += s16[r + 4];
                float rs = (s16[0] + s16[1]) + (s16[2] + s16[3]);
                rs += __shfl_xor(rs, 32);
                l_r += rs;

                // ---- P -> bf16 B-frags via cvt_pk + cross-half shfl exchange ----
                bf16x8 pf[4];
                #pragma unroll
                for (int b2 = 0; b2 < 2; ++b2) {
                    unsigned W[4][2];
                    #pragma unroll
                    for (int c = 0; c < 4; ++c) {
                        float v0 = b2 ? st1[4 * c + 0] : st0[4 * c + 0];
                        float v1 = b2 ? st1[4 * c + 1] : st0[4 * c + 1];
                        float v2 = b2 ? st1[4 * c + 2] : st0[4 * c + 2];
                        float v3 = b2 ? st1[4 * c + 3] : st0[4 * c + 3];
                        W[c][0] = cvtpk(v0, v1);
                        W[c][1] = cvtpk(v2, v3);
                    }
                    #pragma unroll
                    for (int m = 0; m < 2; ++m) {
                        unsigned s0 = hi2 ? W[2 * m][0] : W[2 * m + 1][0];
                        unsigned s1 = hi2 ? W[2 * m][1] : W[2 * m + 1][1];
                        unsigned r0 = (unsigned)__shfl_xor((int)s0, 32);
                        unsigned r1 = (unsigned)__shfl_xor((int)s1, 32);
                        int4 fw;
                        fw.x = (int)(hi2 ? r0 : W[2 * m][0]);
                        fw.y = (int)(hi2 ? r1 : W[2 * m][1]);
                        fw.z = (int)(hi2 ? W[2 * m + 1][0] : r0);
                        fw.w = (int)(hi2 ? W[2 * m + 1][1] : r1);
                        pf[b2 * 2 + m] = __builtin_bit_cast(bf16x8, fw);
                    }
                }

                // ---- PV: O^T += V^T P^T ----
                __builtin_amdgcn_s_setprio(1);
                #pragma unroll
                for (int mm = 0; mm < 4; ++mm) {
                    bf16x8 va0 = *(const bf16x8*)&lds[vbuf +
                        swz((unsigned)l31, (unsigned)(mm * 32 + hi2 * 16))];
                    bf16x8 va1 = *(const bf16x8*)&lds[vbuf +
                        swz((unsigned)(32 + l31), (unsigned)(mm * 32 + hi2 * 16))];
                    acc0 = __builtin_amdgcn_mfma_f32_32x32x16_bf16(va0, pf[mm], acc0, 0, 0, 0);
                    acc1 = __builtin_amdgcn_mfma_f32_32x32x16_bf16(va1, pf[mm], acc1, 0, 0, 0);
                }
                __builtin_amdgcn_s_setprio(0);
            }
        }

        // ---- merge the two kv-parity partials via LDS (flash combine) ----
        __builtin_amdgcn_s_barrier();                   // all LDS reads of this phase done
        const unsigned mbase = (unsigned)rg * (64u * 144u) + (unsigned)lane * 144u;
        if (par == 1) {
            #pragma unroll
            for (int c = 0; c < 4; ++c) {
                f32x4 q0 = {acc0[4 * c], acc0[4 * c + 1], acc0[4 * c + 2], acc0[4 * c + 3]};
                *(f32x4*)&lds[mbase + c * 16] = q0;
                f32x4 q1 = {acc1[4 * c], acc1[4 * c + 1], acc1[4 * c + 2], acc1[4 * c + 3]};
                *(f32x4*)&lds[mbase + 64 + c * 16] = q1;
            }
            *(float*)&lds[mbase + 128] = m_r;
            *(float*)&lds[mbase + 132] = l_r;
        }
        __builtin_amdgcn_s_barrier();
        if (par == 0) {
            float m2 = *(const float*)&lds[mbase + 128];
            float l2 = *(const float*)&lds[mbase + 132];
            float m  = fmaxf(m_r, m2);
            float a1 = fexp2(m_r - m);
            float a2 = fexp2(m2 - m);
            float l  = a1 * l_r + a2 * l2;
            float inv = 1.f / l;
            #pragma unroll
            for (int c = 0; c < 4; ++c) {
                f32x4 p0 = *(const f32x4*)&lds[mbase + c * 16];
                f32x4 p1 = *(const f32x4*)&lds[mbase + 64 + c * 16];
                float4 o0, o1;
                o0.x = (a1 * acc0[4 * c + 0] + a2 * p0[0]) * inv;
                o0.y = (a1 * acc0[4 * c + 1] + a2 * p0[1]) * inv;
                o0.z = (a1 * acc0[4 * c + 2] + a2 * p0[2]) * inv;
                o0.w = (a1 * acc0[4 * c + 3] + a2 * p0[3]) * inv;
                o1.x = (a1 * acc1[4 * c + 0] + a2 * p1[0]) * inv;
                o1.y = (a1 * acc1[4 * c + 1] + a2 * p1[1]) * inv;
                o1.z = (a1 * acc1[4 * c + 2] + a2 * p1[2]) * inv;
                o1.w = (a1 * acc1[4 * c + 3] + a2 * p1[3]) * inv;
                *(float4*)(op + (size_t)qg * D_DIM + 8 * c + 4 * hi2) = o0;
                *(float4*)(op + (size_t)qg * D_DIM + 32 + 8 * c + 4 * hi2) = o1;
            }
        }
        __builtin_amdgcn_s_barrier();   // merge reads done before next phase's staging
    }
}

// ---------------- fallback (round-1 proven) if ws too small ----------------
__global__ __launch_bounds__(256) void attn_fwd_fb(
    const float* __restrict__ Qp, const float* __restrict__ Kp,
    const float* __restrict__ Vp, float* __restrict__ Op, int S)
{
    __shared__ __align__(16) unsigned char lds_k[64 * 128];
    __shared__ __align__(16) unsigned char lds_vt[64 * 128];
    __shared__ __align__(16) unsigned char lds_p[4 * 16 * 128];

    const int qt = blockIdx.x, bh = blockIdx.y, tid = threadIdx.x;
    const int w = tid >> 6, lane = tid & 63, lo = lane & 15, hi = lane >> 4;
    const size_t base = (size_t)bh * S * D_DIM;
    const float* qp = Qp + base; const float* kp = Kp + base;
    const float* vp = Vp + base; float* op = Op + base;
    const int qw = qt * 64 + w * 16;

    auto swzl = [](unsigned row, unsigned colByte) {
        return (row * 128u + colByte) ^ ((row & 7u) << 4);
    };

    bf16x8 qf[2];
    {
        const float* src = qp + (size_t)(qw + lo) * D_DIM + hi * 8;
        #pragma unroll
        for (int f = 0; f < 2; ++f) {
            float4 a = *(const float4*)(src + f * 32);
            float4 b = *(const float4*)(src + f * 32 + 4);
            bf16x8 v;
            v[0] = (short)f2bf(a.x * 0.125f); v[1] = (short)f2bf(a.y * 0.125f);
            v[2] = (short)f2bf(a.z * 0.125f); v[3] = (short)f2bf(a.w * 0.125f);
            v[4] = (short)f2bf(b.x * 0.125f); v[5] = (short)f2bf(b.y * 0.125f);
            v[6] = (short)f2bf(b.z * 0.125f); v[7] = (short)f2bf(b.w * 0.125f);
            qf[f] = v;
        }
    }
    f32x4 o_acc[4]; float m_r[4], l_r[4];
    #pragma unroll
    for (int r = 0; r < 4; ++r) { m_r[r] = -__builtin_inff(); l_r[r] = 0.f; }
    #pragma unroll
    for (int dt = 0; dt < 4; ++dt) o_acc[dt] = (f32x4){0.f, 0.f, 0.f, 0.f};
    const unsigned pbase = (unsigned)w * 2048u;

    for (int t = 0; t <= qt; ++t) {
        const size_t kv0 = (size_t)t * 64;
        __syncthreads();
        #pragma unroll
        for (int jj = 0; jj < 4; ++jj) {
            int n = tid + 256 * jj;
            int r = n >> 4, c = (n & 15) << 2;
            float4 kk = *(const float4*)(kp + (kv0 + r) * D_DIM + c);
            bf16x4 kbv;
            kbv[0] = (short)f2bf(kk.x); kbv[1] = (short)f2bf(kk.y);
            kbv[2] = (short)f2bf(kk.z); kbv[3] = (short)f2bf(kk.w);
            *(bf16x4*)&lds_k[swzl((unsigned)r, (unsigned)c * 2)] = kbv;
            float4 vv = *(const float4*)(vp + (kv0 + r) * D_DIM + c);
            *(unsigned short*)&lds_vt[swzl((unsigned)(c + 0), (unsigned)r * 2)] = f2bf(vv.x);
            *(unsigned short*)&lds_vt[swzl((unsigned)(c + 1), (unsigned)r * 2)] = f2bf(vv.y);
            *(unsigned short*)&lds_vt[swzl((unsigned)(c + 2), (unsigned)r * 2)] = f2bf(vv.z);
            *(unsigned short*)&lds_vt[swzl((unsigned)(c + 3), (unsigned)r * 2)] = f2bf(vv.w);
        }
        __syncthreads();

        float sc[4][4];
        #pragma unroll
        for (int kc = 0; kc < 4; ++kc) {
            f32x4 s = (f32x4){0.f, 0.f, 0.f, 0.f};
            #pragma unroll
            for (int f = 0; f < 2; ++f) {
                bf16x8 kfv = *(const bf16x8*)&lds_k[swzl((unsigned)(kc * 16 + lo),
                                                         (unsigned)(hi * 16 + f * 64))];
                s = __builtin_amdgcn_mfma_f32_16x16x32_bf16(qf[f], kfv, s, 0, 0, 0);
            }
            #pragma unroll
            for (int r = 0; r < 4; ++r) sc[kc][r] = s[r];
        }
        if (t == qt) {
            #pragma unroll
            for (int kc = 0; kc < 4; ++kc)
                #pragma unroll
                for (int r = 0; r < 4; ++r) {
                    int qg2 = w * 16 + hi * 4 + r, kg = kc * 16 + lo;
                    if (kg > qg2) sc[kc][r] = -__builtin_inff();
                }
        }
        float scale[4];
        #pragma unroll
        for (int r = 0; r < 4; ++r) {
            float mx = fmaxf(fmaxf(sc[0][r], sc[1][r]), fmaxf(sc[2][r], sc[3][r]));
            mx = fmaxf(mx, __shfl_xor(mx, 1)); mx = fmaxf(mx, __shfl_xor(mx, 2));
            mx = fmaxf(mx, __shfl_xor(mx, 4)); mx = fmaxf(mx, __shfl_xor(mx, 8));
            float mn = fmaxf(m_r[r], mx);
            scale[r] = __expf(m_r[r] - mn); m_r[r] = mn;
            float s0 = 0.f;
            #pragma unroll
            for (int kc = 0; kc < 4; ++kc) {
                float pv = __expf(sc[kc][r] - mn); sc[kc][r] = pv; s0 += pv;
            }
            s0 += __shfl_xor(s0, 1); s0 += __shfl_xor(s0, 2);
            s0 += __shfl_xor(s0, 4); s0 += __shfl_xor(s0, 8);
            l_r[r] = l_r[r] * scale[r] + s0;
        }
        #pragma unroll
        for (int r = 0; r < 4; ++r) {
            unsigned qr = (unsigned)(hi * 4 + r);
            #pragma unroll
            for (int kc = 0; kc < 4; ++kc)
                *(unsigned short*)&lds_p[pbase + swzl(qr, (unsigned)((kc * 16 + lo) * 2))] =
                    f2bf(sc[kc][r]);
            #pragma unroll
            for (int dt = 0; dt < 4; ++dt) o_acc[dt][r] *= scale[r];
        }
        bf16x8 pa0 = *(const bf16x8*)&lds_p[pbase + swzl((unsigned)lo, (unsigned)(hi * 16))];
        bf16x8 pa1 = *(const bf16x8*)&lds_p[pbase + swzl((unsigned)lo, (unsigned)(hi * 16 + 64))];
        #pragma unroll
        for (int dt = 0; dt < 4; ++dt) {
            bf16x8 vb0 = *(const bf16x8*)&lds_vt[swzl((unsigned)(dt * 16 + lo), (unsigned)(hi * 16))];
            bf16x8 vb1 = *(const bf16x8*)&lds_vt[swzl((unsigned)(dt * 16 + lo), (unsigned)(hi * 16 + 64))];
            o_acc[dt] = __builtin_amdgcn_mfma_f32_16x16x32_bf16(pa0, vb0, o_acc[dt], 0, 0, 0);
            o_acc[dt] = __builtin_amdgcn_mfma_f32_16x16x32_bf16(pa1, vb1, o_acc[dt], 0, 0, 0);
        }
    }
    const int qrow = qw + hi * 4;
    #pragma unroll
    for (int r = 0; r < 4; ++r) {
        float inv = 1.f / l_r[r];
        #pragma unroll
        for (int dt = 0; dt < 4; ++dt)
            op[(size_t)(qrow + r) * D_DIM + dt * 16 + lo] = o_acc[dt][r] * inv;
    }
}

extern "C" void kernel_launch(void* const* d_in, const int* in_sizes, int n_in,
                              void* d_out, int out_size, void* d_ws, size_t ws_size,
                              hipStream_t stream) {
    const float* q = (const float*)d_in[0];
    const float* k = (const float*)d_in[1];
    const float* v = (const float*)d_in[2];
    float* o = (float*)d_out;

    const size_t nelem = (size_t)32 * BHD;                    // 4,194,304 per tensor
    const size_t need = 2 * nelem * sizeof(unsigned short);   // 16 MiB

    if (ws_size >= need) {
        unsigned short* kbf = (unsigned short*)d_ws;
        unsigned short* vtb = kbf + nelem;
        prep_kernel<<<dim3(32, 32), 256, 0, stream>>>(k, v, kbf, vtb);
        attn_pair<<<512, 256, 0, stream>>>(q, kbf, vtb, o);
    } else {
        attn_fwd_fb<<<dim3(32, 32), 256, 0, stream>>>(q, k, v, o, SEQ);
    }
}

// Round 15
// 48.443 us; speedup vs baseline: 1.0695x; 1.0695x over previous
//
#include <hip/hip_runtime.h>
#include <hip/hip_bf16.h>

typedef short bf16x8 __attribute__((ext_vector_type(8)));
typedef short bf16x4 __attribute__((ext_vector_type(4)));
typedef float f32x4  __attribute__((ext_vector_type(4)));
typedef float f32x16 __attribute__((ext_vector_type(16)));

#define D_DIM 64
#define SEQ 2048
#define BHD (SEQ * D_DIM)
#define SCALE_L2E 0.1803368801111204f   // (1/8) * log2(e)

__device__ __forceinline__ unsigned short f2bf(float f) {
    unsigned u = __builtin_bit_cast(unsigned, f);
    u += 0x7fffu + ((u >> 16) & 1u);
    return (unsigned short)(u >> 16);
}
// XOR-swizzle for row-major [R][64] bf16 tiles (row stride 128B) — T2
__device__ __forceinline__ unsigned swz(unsigned row, unsigned colByte) {
    return (row * 128u + colByte) ^ ((row & 7u) << 4);
}
__device__ __forceinline__ void gl_lds(const unsigned short* g, unsigned char* lds_generic,
                                       unsigned lds_off) {
    __builtin_amdgcn_global_load_lds(
        (const __attribute__((address_space(1))) void*)g,
        (__attribute__((address_space(3))) void*)(lds_generic + lds_off), 16, 0, 0);
}
__device__ __forceinline__ float fexp2(float x) {
    float r; asm("v_exp_f32 %0, %1" : "=v"(r) : "v"(x)); return r;
}
__device__ __forceinline__ unsigned cvtpk(float lo, float hi) {
    unsigned r; asm("v_cvt_pk_bf16_f32 %0, %1, %2" : "=v"(r) : "v"(lo), "v"(hi)); return r;
}

// ---------------- fused prepass: K fp32->bf16, V fp32 [s][d] -> Vt bf16 [d][s] ----------------
__global__ __launch_bounds__(256) void prep_kernel(const float* __restrict__ K,
                                                   const float* __restrict__ V,
                                                   unsigned short* __restrict__ Kb,
                                                   unsigned short* __restrict__ Vt) {
    __shared__ unsigned short t[64][66];
    const int st = blockIdx.x;
    const int bh = blockIdx.y;
    const int tid = threadIdx.x;
    const size_t base = (size_t)bh * BHD;

    const float* ksrc = K + base + st * 4096;
    unsigned short* kdst = Kb + base + st * 4096;
    #pragma unroll
    for (int j = 0; j < 2; ++j) {
        int e = (j * 256 + tid) * 8;
        float4 a = *(const float4*)(ksrc + e);
        float4 b = *(const float4*)(ksrc + e + 4);
        bf16x8 o;
        o[0] = (short)f2bf(a.x); o[1] = (short)f2bf(a.y);
        o[2] = (short)f2bf(a.z); o[3] = (short)f2bf(a.w);
        o[4] = (short)f2bf(b.x); o[5] = (short)f2bf(b.y);
        o[6] = (short)f2bf(b.z); o[7] = (short)f2bf(b.w);
        *(bf16x8*)(kdst + e) = o;
    }

    const float* vb = V + base + st * 64 * D_DIM;
    #pragma unroll
    for (int j = 0; j < 4; ++j) {
        int n = tid + 256 * j;
        int r = n >> 4;
        int c = (n & 15) << 2;
        float4 v = *(const float4*)(vb + r * D_DIM + c);
        t[r][c + 0] = f2bf(v.x); t[r][c + 1] = f2bf(v.y);
        t[r][c + 2] = f2bf(v.z); t[r][c + 3] = f2bf(v.w);
    }
    __syncthreads();
    #pragma unroll
    for (int j = 0; j < 2; ++j) {
        int m = tid + 256 * j;
        int d = m >> 3;
        int s8 = (m & 7) << 3;
        bf16x8 o;
        #pragma unroll
        for (int e = 0; e < 8; ++e) o[e] = (short)t[s8 + e][d];
        *(bf16x8*)(Vt + base + (size_t)d * SEQ + st * 64 + s8) = o;
    }
}

// ---------------- main: round-13 proven kernel (session-stable optimum) ----------------
// 512 thr = 8 waves, ONE 128-row q-tile. Waves 0-3: even kv-tiles; waves 4-7 (same
// q-rows): odd kv-tiles. Partials merged via LDS at the end (flash combine).
// max3-shaped max tree; defer path (T13) skips the cross-half shfl.
__global__ __launch_bounds__(512, 4) void attn_fwd(const float* __restrict__ Qp,
                                                   const unsigned short* __restrict__ Kb,
                                                   const unsigned short* __restrict__ Vtb,
                                                   float* __restrict__ Op) {
    __shared__ __align__(16) unsigned char lds[65536];  // 2 bufs x (Ke|Ve|Ko|Vo) 8KB each

    int id = blockIdx.y * gridDim.x + blockIdx.x;   // grid (16,32) -> 0..511
    int j  = id >> 3;
    const int bh = (id & 7) * 4 + (j >> 4);
    const int jq = j & 15;
    const int qtile = (j < 32) ? (15 - jq) : jq;

    const int tid  = threadIdx.x;
    const int w    = tid >> 6;
    const int lane = tid & 63;
    const int l31  = lane & 31;
    const int hi2  = lane >> 5;
    const int wsub = w & 3;
    const int par  = w >> 2;                        // kv parity this wave handles

    const int qlo = qtile * 128 + wsub * 32;
    const int t_w = qlo >> 6;
    const int qg  = qlo + l31;
    const int nt  = qtile + 1;

    const size_t base = (size_t)bh * BHD;
    const float* qp = Qp + base;
    const unsigned short* kb = Kb + base;
    const unsigned short* vt = Vtb + base;
    float* op = Op + base;

    const int srow = tid >> 3;
    const int scb  = ((tid & 7) << 4) ^ ((srow & 7) << 4);
    const int kOff = srow * D_DIM + (scb >> 1);
    const int vOff = srow * SEQ + (scb >> 1);
    const unsigned sdst = (unsigned)tid * 16u;

    auto STAGE = [&](int it) {          // stages tiles (2*it, 2*it+1) into buf it&1
        unsigned bb = (unsigned)(it & 1) * 32768u;
        const unsigned short* kg = kb + (size_t)(2 * it) * 4096 + kOff;
        const unsigned short* vg = vt + (size_t)(2 * it) * 64 + vOff;
        gl_lds(kg, lds, bb + sdst);
        gl_lds(vg, lds, bb + 8192u + sdst);
        gl_lds(kg + 4096, lds, bb + 16384u + sdst);
        gl_lds(vg + 64, lds, bb + 24576u + sdst);
    };

    const float* qsrc = qp + (size_t)qg * D_DIM + hi2 * 8;
    float4 qraw[8];
    #pragma unroll
    for (int dk = 0; dk < 4; ++dk) {
        qraw[2 * dk]     = *(const float4*)(qsrc + dk * 16);
        qraw[2 * dk + 1] = *(const float4*)(qsrc + dk * 16 + 4);
    }
    STAGE(0);

    bf16x8 qB[4];
    #pragma unroll
    for (int dk = 0; dk < 4; ++dk) {
        float4 a = qraw[2 * dk], b = qraw[2 * dk + 1];
        bf16x8 v;
        v[0] = (short)f2bf(a.x * SCALE_L2E); v[1] = (short)f2bf(a.y * SCALE_L2E);
        v[2] = (short)f2bf(a.z * SCALE_L2E); v[3] = (short)f2bf(a.w * SCALE_L2E);
        v[4] = (short)f2bf(b.x * SCALE_L2E); v[5] = (short)f2bf(b.y * SCALE_L2E);
        v[6] = (short)f2bf(b.z * SCALE_L2E); v[7] = (short)f2bf(b.w * SCALE_L2E);
        qB[dk] = v;
    }

    f32x16 acc0 = {}, acc1 = {};
    float m_r = -3.0e38f, l_r = 0.f;

    #pragma unroll 1
    for (int it = 0; it < nt; ++it) {
        asm volatile("s_waitcnt vmcnt(0)" ::: "memory");
        __builtin_amdgcn_s_barrier();
        __builtin_amdgcn_sched_barrier(0);
        if (it + 1 < nt) STAGE(it + 1);

        const int tile = 2 * it + par;
        if (tile <= t_w) {                         // wave-uniform
            const unsigned kbuf = (unsigned)(it & 1) * 32768u + (unsigned)par * 16384u;
            const unsigned vbuf = kbuf + 8192u;

            // ---- QK: St[kv][q], A = K rows, B = Q cols ----
            f32x16 st0 = {}, st1 = {};
            __builtin_amdgcn_s_setprio(1);
            #pragma unroll
            for (int dk = 0; dk < 4; ++dk) {
                bf16x8 k0 = *(const bf16x8*)&lds[kbuf +
                    swz((unsigned)l31, (unsigned)(dk * 32 + hi2 * 16))];
                bf16x8 k1 = *(const bf16x8*)&lds[kbuf +
                    swz((unsigned)(32 + l31), (unsigned)(dk * 32 + hi2 * 16))];
                st0 = __builtin_amdgcn_mfma_f32_32x32x16_bf16(k0, qB[dk], st0, 0, 0, 0);
                st1 = __builtin_amdgcn_mfma_f32_32x32x16_bf16(k1, qB[dk], st1, 0, 0, 0);
            }
            __builtin_amdgcn_s_setprio(0);

            // ---- causal mask (diagonal tile only) ----
            if (tile == t_w) {
                #pragma unroll
                for (int r = 0; r < 16; ++r) {
                    int kvb = tile * 64 + (r & 3) + 8 * (r >> 2) + 4 * hi2;
                    if (kvb > qg)      st0[r] = -3.0e38f;
                    if (kvb + 32 > qg) st1[r] = -3.0e38f;
                }
            }

            // ---- half-max via max3-shaped triples (no cross-half shfl on defer path) ----
            float m8[8];
            #pragma unroll
            for (int r = 0; r < 8; ++r)
                m8[r] = fmaxf(fmaxf(fmaxf(st0[r], st0[r + 8]), st1[r]), st1[r + 8]);
            float mx = fmaxf(fmaxf(fmaxf(m8[0], m8[1]), m8[2]),
                             fmaxf(fmaxf(m8[3], m8[4]),
                                   fmaxf(fmaxf(m8[5], m8[6]), m8[7])));

            // ---- defer-max (T13): __all over 64 lanes covers both halves of each row ----
            float mn;
            if (__all(mx <= m_r + 8.0f)) {
                mn = m_r;
            } else {
                float mfull = fmaxf(mx, __shfl_xor(mx, 32));   // rare path (proven shfl)
                mn = fmaxf(m_r, mfull);
                float sc = fexp2(m_r - mn);
                m_r = mn;
                l_r *= sc;
                #pragma unroll
                for (int r = 0; r < 16; ++r) { acc0[r] *= sc; acc1[r] *= sc; }
            }

            // ---- exp (in place) + sum tree ----
            #pragma unroll
            for (int r = 0; r < 16; ++r) st0[r] = fexp2(st0[r] - mn);
            #pragma unroll
            for (int r = 0; r < 16; ++r) st1[r] = fexp2(st1[r] - mn);
            float s16[16];
            #pragma unroll
            for (int r = 0; r < 16; ++r) s16[r] = st0[r] + st1[r];
            #pragma unroll
            for (int r = 0; r < 8; ++r) s16[r] += s16[r + 8];
            #pragma unroll
            for (int r = 0; r < 4; ++r) s16[r] += s16[r + 4];
            float rs = (s16[0] + s16[1]) + (s16[2] + s16[3]);
            rs += __shfl_xor(rs, 32);
            l_r += rs;

            // ---- P -> bf16 B-frags via cvt_pk + cross-half shfl exchange (proven) ----
            bf16x8 pf[4];
            #pragma unroll
            for (int b2 = 0; b2 < 2; ++b2) {
                unsigned W[4][2];
                #pragma unroll
                for (int c = 0; c < 4; ++c) {
                    float v0 = b2 ? st1[4 * c + 0] : st0[4 * c + 0];
                    float v1 = b2 ? st1[4 * c + 1] : st0[4 * c + 1];
                    float v2 = b2 ? st1[4 * c + 2] : st0[4 * c + 2];
                    float v3 = b2 ? st1[4 * c + 3] : st0[4 * c + 3];
                    W[c][0] = cvtpk(v0, v1);
                    W[c][1] = cvtpk(v2, v3);
                }
                #pragma unroll
                for (int m = 0; m < 2; ++m) {
                    unsigned s0 = hi2 ? W[2 * m][0] : W[2 * m + 1][0];
                    unsigned s1 = hi2 ? W[2 * m][1] : W[2 * m + 1][1];
                    unsigned r0 = (unsigned)__shfl_xor((int)s0, 32);
                    unsigned r1 = (unsigned)__shfl_xor((int)s1, 32);
                    int4 fw;
                    fw.x = (int)(hi2 ? r0 : W[2 * m][0]);
                    fw.y = (int)(hi2 ? r1 : W[2 * m][1]);
                    fw.z = (int)(hi2 ? W[2 * m + 1][0] : r0);
                    fw.w = (int)(hi2 ? W[2 * m + 1][1] : r1);
                    pf[b2 * 2 + m] = __builtin_bit_cast(bf16x8, fw);
                }
            }

            // ---- PV: O^T += V^T P^T ----
            __builtin_amdgcn_s_setprio(1);
            #pragma unroll
            for (int mm = 0; mm < 4; ++mm) {
                bf16x8 va0 = *(const bf16x8*)&lds[vbuf +
                    swz((unsigned)l31, (unsigned)(mm * 32 + hi2 * 16))];
                bf16x8 va1 = *(const bf16x8*)&lds[vbuf +
                    swz((unsigned)(32 + l31), (unsigned)(mm * 32 + hi2 * 16))];
                acc0 = __builtin_amdgcn_mfma_f32_32x32x16_bf16(va0, pf[mm], acc0, 0, 0, 0);
                acc1 = __builtin_amdgcn_mfma_f32_32x32x16_bf16(va1, pf[mm], acc1, 0, 0, 0);
            }
            __builtin_amdgcn_s_setprio(0);
        }
    }

    // ---- merge the two kv-parity partials (flash combine, exp2 domain) ----
    __builtin_amdgcn_s_barrier();                       // all compute (incl. LDS reads) done
    const unsigned mbase = (unsigned)wsub * (64u * 144u) + (unsigned)lane * 144u;
    if (w >= 4) {
        #pragma unroll
        for (int c = 0; c < 4; ++c) {
            f32x4 q0 = {acc0[4 * c], acc0[4 * c + 1], acc0[4 * c + 2], acc0[4 * c + 3]};
            *(f32x4*)&lds[mbase + c * 16] = q0;
            f32x4 q1 = {acc1[4 * c], acc1[4 * c + 1], acc1[4 * c + 2], acc1[4 * c + 3]};
            *(f32x4*)&lds[mbase + 64 + c * 16] = q1;
        }
        *(float*)&lds[mbase + 128] = m_r;
        *(float*)&lds[mbase + 132] = l_r;
    }
    __builtin_amdgcn_s_barrier();
    if (w < 4) {
        float m2 = *(const float*)&lds[mbase + 128];
        float l2 = *(const float*)&lds[mbase + 132];
        float m  = fmaxf(m_r, m2);
        float a1 = fexp2(m_r - m);
        float a2 = fexp2(m2 - m);
        float l  = a1 * l_r + a2 * l2;
        float inv = 1.f / l;
        #pragma unroll
        for (int c = 0; c < 4; ++c) {
            f32x4 p0 = *(const f32x4*)&lds[mbase + c * 16];
            f32x4 p1 = *(const f32x4*)&lds[mbase + 64 + c * 16];
            float4 o0, o1;
            o0.x = (a1 * acc0[4 * c + 0] + a2 * p0[0]) * inv;
            o0.y = (a1 * acc0[4 * c + 1] + a2 * p0[1]) * inv;
            o0.z = (a1 * acc0[4 * c + 2] + a2 * p0[2]) * inv;
            o0.w = (a1 * acc0[4 * c + 3] + a2 * p0[3]) * inv;
            o1.x = (a1 * acc1[4 * c + 0] + a2 * p1[0]) * inv;
            o1.y = (a1 * acc1[4 * c + 1] + a2 * p1[1]) * inv;
            o1.z = (a1 * acc1[4 * c + 2] + a2 * p1[2]) * inv;
            o1.w = (a1 * acc1[4 * c + 3] + a2 * p1[3]) * inv;
            *(float4*)(op + (size_t)qg * D_DIM + 8 * c + 4 * hi2) = o0;
            *(float4*)(op + (size_t)qg * D_DIM + 32 + 8 * c + 4 * hi2) = o1;
        }
    }
}

// ---------------- fallback (round-1 proven) if ws too small ----------------
__global__ __launch_bounds__(256) void attn_fwd_fb(
    const float* __restrict__ Qp, const float* __restrict__ Kp,
    const float* __restrict__ Vp, float* __restrict__ Op, int S)
{
    __shared__ __align__(16) unsigned char lds_k[64 * 128];
    __shared__ __align__(16) unsigned char lds_vt[64 * 128];
    __shared__ __align__(16) unsigned char lds_p[4 * 16 * 128];

    const int qt = blockIdx.x, bh = blockIdx.y, tid = threadIdx.x;
    const int w = tid >> 6, lane = tid & 63, lo = lane & 15, hi = lane >> 4;
    const size_t base = (size_t)bh * S * D_DIM;
    const float* qp = Qp + base; const float* kp = Kp + base;
    const float* vp = Vp + base; float* op = Op + base;
    const int qw = qt * 64 + w * 16;

    auto swzl = [](unsigned row, unsigned colByte) {
        return (row * 128u + colByte) ^ ((row & 7u) << 4);
    };

    bf16x8 qf[2];
    {
        const float* src = qp + (size_t)(qw + lo) * D_DIM + hi * 8;
        #pragma unroll
        for (int f = 0; f < 2; ++f) {
            float4 a = *(const float4*)(src + f * 32);
            float4 b = *(const float4*)(src + f * 32 + 4);
            bf16x8 v;
            v[0] = (short)f2bf(a.x * 0.125f); v[1] = (short)f2bf(a.y * 0.125f);
            v[2] = (short)f2bf(a.z * 0.125f); v[3] = (short)f2bf(a.w * 0.125f);
            v[4] = (short)f2bf(b.x * 0.125f); v[5] = (short)f2bf(b.y * 0.125f);
            v[6] = (short)f2bf(b.z * 0.125f); v[7] = (short)f2bf(b.w * 0.125f);
            qf[f] = v;
        }
    }
    f32x4 o_acc[4]; float m_r[4], l_r[4];
    #pragma unroll
    for (int r = 0; r < 4; ++r) { m_r[r] = -__builtin_inff(); l_r[r] = 0.f; }
    #pragma unroll
    for (int dt = 0; dt < 4; ++dt) o_acc[dt] = (f32x4){0.f, 0.f, 0.f, 0.f};
    const unsigned pbase = (unsigned)w * 2048u;

    for (int t = 0; t <= qt; ++t) {
        const size_t kv0 = (size_t)t * 64;
        __syncthreads();
        #pragma unroll
        for (int jj = 0; jj < 4; ++jj) {
            int n = tid + 256 * jj;
            int r = n >> 4, c = (n & 15) << 2;
            float4 kk = *(const float4*)(kp + (kv0 + r) * D_DIM + c);
            bf16x4 kbv;
            kbv[0] = (short)f2bf(kk.x); kbv[1] = (short)f2bf(kk.y);
            kbv[2] = (short)f2bf(kk.z); kbv[3] = (short)f2bf(kk.w);
            *(bf16x4*)&lds_k[swzl((unsigned)r, (unsigned)c * 2)] = kbv;
            float4 vv = *(const float4*)(vp + (kv0 + r) * D_DIM + c);
            *(unsigned short*)&lds_vt[swzl((unsigned)(c + 0), (unsigned)r * 2)] = f2bf(vv.x);
            *(unsigned short*)&lds_vt[swzl((unsigned)(c + 1), (unsigned)r * 2)] = f2bf(vv.y);
            *(unsigned short*)&lds_vt[swzl((unsigned)(c + 2), (unsigned)r * 2)] = f2bf(vv.z);
            *(unsigned short*)&lds_vt[swzl((unsigned)(c + 3), (unsigned)r * 2)] = f2bf(vv.w);
        }
        __syncthreads();

        float sc[4][4];
        #pragma unroll
        for (int kc = 0; kc < 4; ++kc) {
            f32x4 s = (f32x4){0.f, 0.f, 0.f, 0.f};
            #pragma unroll
            for (int f = 0; f < 2; ++f) {
                bf16x8 kfv = *(const bf16x8*)&lds_k[swzl((unsigned)(kc * 16 + lo),
                                                         (unsigned)(hi * 16 + f * 64))];
                s = __builtin_amdgcn_mfma_f32_16x16x32_bf16(qf[f], kfv, s, 0, 0, 0);
            }
            #pragma unroll
            for (int r = 0; r < 4; ++r) sc[kc][r] = s[r];
        }
        if (t == qt) {
            #pragma unroll
            for (int kc = 0; kc < 4; ++kc)
                #pragma unroll
                for (int r = 0; r < 4; ++r) {
                    int qg2 = w * 16 + hi * 4 + r, kg = kc * 16 + lo;
                    if (kg > qg2) sc[kc][r] = -__builtin_inff();
                }
        }
        float scale[4];
        #pragma unroll
        for (int r = 0; r < 4; ++r) {
            float mx = fmaxf(fmaxf(sc[0][r], sc[1][r]), fmaxf(sc[2][r], sc[3][r]));
            mx = fmaxf(mx, __shfl_xor(mx, 1)); mx = fmaxf(mx, __shfl_xor(mx, 2));
            mx = fmaxf(mx, __shfl_xor(mx, 4)); mx = fmaxf(mx, __shfl_xor(mx, 8));
            float mn = fmaxf(m_r[r], mx);
            scale[r] = __expf(m_r[r] - mn); m_r[r] = mn;
            float s0 = 0.f;
            #pragma unroll
            for (int kc = 0; kc < 4; ++kc) {
                float pv = __expf(sc[kc][r] - mn); sc[kc][r] = pv; s0 += pv;
            }
            s0 += __shfl_xor(s0, 1); s0 += __shfl_xor(s0, 2);
            s0 += __shfl_xor(s0, 4); s0 += __shfl_xor(s0, 8);
            l_r[r] = l_r[r] * scale[r] + s0;
        }
        #pragma unroll
        for (int r = 0; r < 4; ++r) {
            unsigned qr = (unsigned)(hi * 4 + r);
            #pragma unroll
            for (int kc = 0; kc < 4; ++kc)
                *(unsigned short*)&lds_p[pbase + swzl(qr, (unsigned)((kc * 16 + lo) * 2))] =
                    f2bf(sc[kc][r]);
            #pragma unroll
            for (int dt = 0; dt < 4; ++dt) o_acc[dt][r] *= scale[r];
        }
        bf16x8 pa0 = *(const bf16x8*)&lds_p[pbase + swzl((unsigned)lo, (unsigned)(hi * 16))];
        bf16x8 pa1 = *(const bf16x8*)&lds_p[pbase + swzl((unsigned)lo, (unsigned)(hi * 16 + 64))];
        #pragma unroll
        for (int dt = 0; dt < 4; ++dt) {
            bf16x8 vb0 = *(const bf16x8*)&lds_vt[swzl((unsigned)(dt * 16 + lo), (unsigned)(hi * 16))];
            bf16x8 vb1 = *(const bf16x8*)&lds_vt[swzl((unsigned)(dt * 16 + lo), (unsigned)(hi * 16 + 64))];
            o_acc[dt] = __builtin_amdgcn_mfma_f32_16x16x32_bf16(pa0, vb0, o_acc[dt], 0, 0, 0);
            o_acc[dt] = __builtin_amdgcn_mfma_f32_16x16x32_bf16(pa1, vb1, o_acc[dt], 0, 0, 0);
        }
    }
    const int qrow = qw + hi * 4;
    #pragma unroll
    for (int r = 0; r < 4; ++r) {
        float inv = 1.f / l_r[r];
        #pragma unroll
        for (int dt = 0; dt < 4; ++dt)
            op[(size_t)(qrow + r) * D_DIM + dt * 16 + lo] = o_acc[dt][r] * inv;
    }
}

extern "C" void kernel_launch(void* const* d_in, const int* in_sizes, int n_in,
                              void* d_out, int out_size, void* d_ws, size_t ws_size,
                              hipStream_t stream) {
    const float* q = (const float*)d_in[0];
    const float* k = (const float*)d_in[1];
    const float* v = (const float*)d_in[2];
    float* o = (float*)d_out;

    const size_t nelem = (size_t)32 * BHD;                    // 4,194,304 per tensor
    const size_t need = 2 * nelem * sizeof(unsigned short);   // 16 MiB

    if (ws_size >= need) {
        unsigned short* kbf = (unsigned short*)d_ws;
        unsigned short* vtb = kbf + nelem;
        prep_kernel<<<dim3(32, 32), 256, 0, stream>>>(k, v, kbf, vtb);
        attn_fwd<<<dim3(16, 32), 512, 0, stream>>>(q, kbf, vtb, o);
    } else {
        attn_fwd_fb<<<dim3(32, 32), 256, 0, stream>>>(q, k, v, o, SEQ);
    }
}

// Round 17
// 48.275 us; speedup vs baseline: 1.0732x; 1.0035x over previous
//
#include <hip/hip_runtime.h>
#include <hip/hip_bf16.h>

typedef short bf16x8 __attribute__((ext_vector_type(8)));
typedef short bf16x4 __attribute__((ext_vector_type(4)));
typedef float f32x4  __attribute__((ext_vector_type(4)));
typedef float f32x16 __attribute__((ext_vector_type(16)));

#define D_DIM 64
#define SEQ 2048
#define BHD (SEQ * D_DIM)
#define SCALE_L2E 0.1803368801111204f   // (1/8) * log2(e)

__device__ __forceinline__ unsigned short f2bf(float f) {
    unsigned u = __builtin_bit_cast(unsigned, f);
    u += 0x7fffu + ((u >> 16) & 1u);
    return (unsigned short)(u >> 16);
}
// XOR-swizzle for row-major [R][64] bf16 tiles (row stride 128B) — T2
__device__ __forceinline__ unsigned swz(unsigned row, unsigned colByte) {
    return (row * 128u + colByte) ^ ((row & 7u) << 4);
}
__device__ __forceinline__ void gl_lds(const unsigned short* g, unsigned char* lds_generic,
                                       unsigned lds_off) {
    __builtin_amdgcn_global_load_lds(
        (const __attribute__((address_space(1))) void*)g,
        (__attribute__((address_space(3))) void*)(lds_generic + lds_off), 16, 0, 0);
}
__device__ __forceinline__ float fexp2(float x) {
    float r; asm("v_exp_f32 %0, %1" : "=v"(r) : "v"(x)); return r;
}
__device__ __forceinline__ unsigned cvtpk(float lo, float hi) {
    unsigned r; asm("v_cvt_pk_bf16_f32 %0, %1, %2" : "=v"(r) : "v"(lo), "v"(hi)); return r;
}

// ---------------- fused prepass: K fp32->bf16, V fp32 [s][d] -> Vt bf16 [d][s] ----------------
__global__ __launch_bounds__(256) void prep_kernel(const float* __restrict__ K,
                                                   const float* __restrict__ V,
                                                   unsigned short* __restrict__ Kb,
                                                   unsigned short* __restrict__ Vt) {
    __shared__ unsigned short t[64][66];
    const int st = blockIdx.x;
    const int bh = blockIdx.y;
    const int tid = threadIdx.x;
    const size_t base = (size_t)bh * BHD;

    const float* ksrc = K + base + st * 4096;
    unsigned short* kdst = Kb + base + st * 4096;
    #pragma unroll
    for (int j = 0; j < 2; ++j) {
        int e = (j * 256 + tid) * 8;
        float4 a = *(const float4*)(ksrc + e);
        float4 b = *(const float4*)(ksrc + e + 4);
        bf16x8 o;
        o[0] = (short)f2bf(a.x); o[1] = (short)f2bf(a.y);
        o[2] = (short)f2bf(a.z); o[3] = (short)f2bf(a.w);
        o[4] = (short)f2bf(b.x); o[5] = (short)f2bf(b.y);
        o[6] = (short)f2bf(b.z); o[7] = (short)f2bf(b.w);
        *(bf16x8*)(kdst + e) = o;
    }

    const float* vb = V + base + st * 64 * D_DIM;
    #pragma unroll
    for (int j = 0; j < 4; ++j) {
        int n = tid + 256 * j;
        int r = n >> 4;
        int c = (n & 15) << 2;
        float4 v = *(const float4*)(vb + r * D_DIM + c);
        t[r][c + 0] = f2bf(v.x); t[r][c + 1] = f2bf(v.y);
        t[r][c + 2] = f2bf(v.z); t[r][c + 3] = f2bf(v.w);
    }
    __syncthreads();
    #pragma unroll
    for (int j = 0; j < 2; ++j) {
        int m = tid + 256 * j;
        int d = m >> 3;
        int s8 = (m & 7) << 3;
        bf16x8 o;
        #pragma unroll
        for (int e = 0; e < 8; ++e) o[e] = (short)t[s8 + e][d];
        *(bf16x8*)(Vt + base + (size_t)d * SEQ + st * 64 + s8) = o;
    }
}

// ---------------- main: round-13 proven kernel (session-final optimum) ----------------
// 512 thr = 8 waves, ONE 128-row q-tile. Waves 0-3: even kv-tiles; waves 4-7 (same
// q-rows): odd kv-tiles. Partials merged via LDS at the end (flash combine).
// max3-shaped max tree; defer path (T13) skips the cross-half shfl.
__global__ __launch_bounds__(512, 4) void attn_fwd(const float* __restrict__ Qp,
                                                   const unsigned short* __restrict__ Kb,
                                                   const unsigned short* __restrict__ Vtb,
                                                   float* __restrict__ Op) {
    __shared__ __align__(16) unsigned char lds[65536];  // 2 bufs x (Ke|Ve|Ko|Vo) 8KB each

    int id = blockIdx.y * gridDim.x + blockIdx.x;   // grid (16,32) -> 0..511
    int j  = id >> 3;
    const int bh = (id & 7) * 4 + (j >> 4);
    const int jq = j & 15;
    const int qtile = (j < 32) ? (15 - jq) : jq;

    const int tid  = threadIdx.x;
    const int w    = tid >> 6;
    const int lane = tid & 63;
    const int l31  = lane & 31;
    const int hi2  = lane >> 5;
    const int wsub = w & 3;
    const int par  = w >> 2;                        // kv parity this wave handles

    const int qlo = qtile * 128 + wsub * 32;
    const int t_w = qlo >> 6;
    const int qg  = qlo + l31;
    const int nt  = qtile + 1;

    const size_t base = (size_t)bh * BHD;
    const float* qp = Qp + base;
    const unsigned short* kb = Kb + base;
    const unsigned short* vt = Vtb + base;
    float* op = Op + base;

    const int srow = tid >> 3;
    const int scb  = ((tid & 7) << 4) ^ ((srow & 7) << 4);
    const int kOff = srow * D_DIM + (scb >> 1);
    const int vOff = srow * SEQ + (scb >> 1);
    const unsigned sdst = (unsigned)tid * 16u;

    auto STAGE = [&](int it) {          // stages tiles (2*it, 2*it+1) into buf it&1
        unsigned bb = (unsigned)(it & 1) * 32768u;
        const unsigned short* kg = kb + (size_t)(2 * it) * 4096 + kOff;
        const unsigned short* vg = vt + (size_t)(2 * it) * 64 + vOff;
        gl_lds(kg, lds, bb + sdst);
        gl_lds(vg, lds, bb + 8192u + sdst);
        gl_lds(kg + 4096, lds, bb + 16384u + sdst);
        gl_lds(vg + 64, lds, bb + 24576u + sdst);
    };

    const float* qsrc = qp + (size_t)qg * D_DIM + hi2 * 8;
    float4 qraw[8];
    #pragma unroll
    for (int dk = 0; dk < 4; ++dk) {
        qraw[2 * dk]     = *(const float4*)(qsrc + dk * 16);
        qraw[2 * dk + 1] = *(const float4*)(qsrc + dk * 16 + 4);
    }
    STAGE(0);

    bf16x8 qB[4];
    #pragma unroll
    for (int dk = 0; dk < 4; ++dk) {
        float4 a = qraw[2 * dk], b = qraw[2 * dk + 1];
        bf16x8 v;
        v[0] = (short)f2bf(a.x * SCALE_L2E); v[1] = (short)f2bf(a.y * SCALE_L2E);
        v[2] = (short)f2bf(a.z * SCALE_L2E); v[3] = (short)f2bf(a.w * SCALE_L2E);
        v[4] = (short)f2bf(b.x * SCALE_L2E); v[5] = (short)f2bf(b.y * SCALE_L2E);
        v[6] = (short)f2bf(b.z * SCALE_L2E); v[7] = (short)f2bf(b.w * SCALE_L2E);
        qB[dk] = v;
    }

    f32x16 acc0 = {}, acc1 = {};
    float m_r = -3.0e38f, l_r = 0.f;

    #pragma unroll 1
    for (int it = 0; it < nt; ++it) {
        asm volatile("s_waitcnt vmcnt(0)" ::: "memory");
        __builtin_amdgcn_s_barrier();
        __builtin_amdgcn_sched_barrier(0);
        if (it + 1 < nt) STAGE(it + 1);

        const int tile = 2 * it + par;
        if (tile <= t_w) {                         // wave-uniform
            const unsigned kbuf = (unsigned)(it & 1) * 32768u + (unsigned)par * 16384u;
            const unsigned vbuf = kbuf + 8192u;

            // ---- QK: St[kv][q], A = K rows, B = Q cols ----
            f32x16 st0 = {}, st1 = {};
            __builtin_amdgcn_s_setprio(1);
            #pragma unroll
            for (int dk = 0; dk < 4; ++dk) {
                bf16x8 k0 = *(const bf16x8*)&lds[kbuf +
                    swz((unsigned)l31, (unsigned)(dk * 32 + hi2 * 16))];
                bf16x8 k1 = *(const bf16x8*)&lds[kbuf +
                    swz((unsigned)(32 + l31), (unsigned)(dk * 32 + hi2 * 16))];
                st0 = __builtin_amdgcn_mfma_f32_32x32x16_bf16(k0, qB[dk], st0, 0, 0, 0);
                st1 = __builtin_amdgcn_mfma_f32_32x32x16_bf16(k1, qB[dk], st1, 0, 0, 0);
            }
            __builtin_amdgcn_s_setprio(0);

            // ---- causal mask (diagonal tile only) ----
            if (tile == t_w) {
                #pragma unroll
                for (int r = 0; r < 16; ++r) {
                    int kvb = tile * 64 + (r & 3) + 8 * (r >> 2) + 4 * hi2;
                    if (kvb > qg)      st0[r] = -3.0e38f;
                    if (kvb + 32 > qg) st1[r] = -3.0e38f;
                }
            }

            // ---- half-max via max3-shaped triples (no cross-half shfl on defer path) ----
            float m8[8];
            #pragma unroll
            for (int r = 0; r < 8; ++r)
                m8[r] = fmaxf(fmaxf(fmaxf(st0[r], st0[r + 8]), st1[r]), st1[r + 8]);
            float mx = fmaxf(fmaxf(fmaxf(m8[0], m8[1]), m8[2]),
                             fmaxf(fmaxf(m8[3], m8[4]),
                                   fmaxf(fmaxf(m8[5], m8[6]), m8[7])));

            // ---- defer-max (T13): __all over 64 lanes covers both halves of each row ----
            float mn;
            if (__all(mx <= m_r + 8.0f)) {
                mn = m_r;
            } else {
                float mfull = fmaxf(mx, __shfl_xor(mx, 32));   // rare path (proven shfl)
                mn = fmaxf(m_r, mfull);
                float sc = fexp2(m_r - mn);
                m_r = mn;
                l_r *= sc;
                #pragma unroll
                for (int r = 0; r < 16; ++r) { acc0[r] *= sc; acc1[r] *= sc; }
            }

            // ---- exp (in place) + sum tree ----
            #pragma unroll
            for (int r = 0; r < 16; ++r) st0[r] = fexp2(st0[r] - mn);
            #pragma unroll
            for (int r = 0; r < 16; ++r) st1[r] = fexp2(st1[r] - mn);
            float s16[16];
            #pragma unroll
            for (int r = 0; r < 16; ++r) s16[r] = st0[r] + st1[r];
            #pragma unroll
            for (int r = 0; r < 8; ++r) s16[r] += s16[r + 8];
            #pragma unroll
            for (int r = 0; r < 4; ++r) s16[r] += s16[r + 4];
            float rs = (s16[0] + s16[1]) + (s16[2] + s16[3]);
            rs += __shfl_xor(rs, 32);
            l_r += rs;

            // ---- P -> bf16 B-frags via cvt_pk + cross-half shfl exchange (proven) ----
            bf16x8 pf[4];
            #pragma unroll
            for (int b2 = 0; b2 < 2; ++b2) {
                unsigned W[4][2];
                #pragma unroll
                for (int c = 0; c < 4; ++c) {
                    float v0 = b2 ? st1[4 * c + 0] : st0[4 * c + 0];
                    float v1 = b2 ? st1[4 * c + 1] : st0[4 * c + 1];
                    float v2 = b2 ? st1[4 * c + 2] : st0[4 * c + 2];
                    float v3 = b2 ? st1[4 * c + 3] : st0[4 * c + 3];
                    W[c][0] = cvtpk(v0, v1);
                    W[c][1] = cvtpk(v2, v3);
                }
                #pragma unroll
                for (int m = 0; m < 2; ++m) {
                    unsigned s0 = hi2 ? W[2 * m][0] : W[2 * m + 1][0];
                    unsigned s1 = hi2 ? W[2 * m][1] : W[2 * m + 1][1];
                    unsigned r0 = (unsigned)__shfl_xor((int)s0, 32);
                    unsigned r1 = (unsigned)__shfl_xor((int)s1, 32);
                    int4 fw;
                    fw.x = (int)(hi2 ? r0 : W[2 * m][0]);
                    fw.y = (int)(hi2 ? r1 : W[2 * m][1]);
                    fw.z = (int)(hi2 ? W[2 * m + 1][0] : r0);
                    fw.w = (int)(hi2 ? W[2 * m + 1][1] : r1);
                    pf[b2 * 2 + m] = __builtin_bit_cast(bf16x8, fw);
                }
            }

            // ---- PV: O^T += V^T P^T ----
            __builtin_amdgcn_s_setprio(1);
            #pragma unroll
            for (int mm = 0; mm < 4; ++mm) {
                bf16x8 va0 = *(const bf16x8*)&lds[vbuf +
                    swz((unsigned)l31, (unsigned)(mm * 32 + hi2 * 16))];
                bf16x8 va1 = *(const bf16x8*)&lds[vbuf +
                    swz((unsigned)(32 + l31), (unsigned)(mm * 32 + hi2 * 16))];
                acc0 = __builtin_amdgcn_mfma_f32_32x32x16_bf16(va0, pf[mm], acc0, 0, 0, 0);
                acc1 = __builtin_amdgcn_mfma_f32_32x32x16_bf16(va1, pf[mm], acc1, 0, 0, 0);
            }
            __builtin_amdgcn_s_setprio(0);
        }
    }

    // ---- merge the two kv-parity partials (flash combine, exp2 domain) ----
    __builtin_amdgcn_s_barrier();                       // all compute (incl. LDS reads) done
    const unsigned mbase = (unsigned)wsub * (64u * 144u) + (unsigned)lane * 144u;
    if (w >= 4) {
        #pragma unroll
        for (int c = 0; c < 4; ++c) {
            f32x4 q0 = {acc0[4 * c], acc0[4 * c + 1], acc0[4 * c + 2], acc0[4 * c + 3]};
            *(f32x4*)&lds[mbase + c * 16] = q0;
            f32x4 q1 = {acc1[4 * c], acc1[4 * c + 1], acc1[4 * c + 2], acc1[4 * c + 3]};
            *(f32x4*)&lds[mbase + 64 + c * 16] = q1;
        }
        *(float*)&lds[mbase + 128] = m_r;
        *(float*)&lds[mbase + 132] = l_r;
    }
    __builtin_amdgcn_s_barrier();
    if (w < 4) {
        float m2 = *(const float*)&lds[mbase + 128];
        float l2 = *(const float*)&lds[mbase + 132];
        float m  = fmaxf(m_r, m2);
        float a1 = fexp2(m_r - m);
        float a2 = fexp2(m2 - m);
        float l  = a1 * l_r + a2 * l2;
        float inv = 1.f / l;
        #pragma unroll
        for (int c = 0; c < 4; ++c) {
            f32x4 p0 = *(const f32x4*)&lds[mbase + c * 16];
            f32x4 p1 = *(const f32x4*)&lds[mbase + 64 + c * 16];
            float4 o0, o1;
            o0.x = (a1 * acc0[4 * c + 0] + a2 * p0[0]) * inv;
            o0.y = (a1 * acc0[4 * c + 1] + a2 * p0[1]) * inv;
            o0.z = (a1 * acc0[4 * c + 2] + a2 * p0[2]) * inv;
            o0.w = (a1 * acc0[4 * c + 3] + a2 * p0[3]) * inv;
            o1.x = (a1 * acc1[4 * c + 0] + a2 * p1[0]) * inv;
            o1.y = (a1 * acc1[4 * c + 1] + a2 * p1[1]) * inv;
            o1.z = (a1 * acc1[4 * c + 2] + a2 * p1[2]) * inv;
            o1.w = (a1 * acc1[4 * c + 3] + a2 * p1[3]) * inv;
            *(float4*)(op + (size_t)qg * D_DIM + 8 * c + 4 * hi2) = o0;
            *(float4*)(op + (size_t)qg * D_DIM + 32 + 8 * c + 4 * hi2) = o1;
        }
    }
}

// ---------------- fallback (round-1 proven) if ws too small ----------------
__global__ __launch_bounds__(256) void attn_fwd_fb(
    const float* __restrict__ Qp, const float* __restrict__ Kp,
    const float* __restrict__ Vp, float* __restrict__ Op, int S)
{
    __shared__ __align__(16) unsigned char lds_k[64 * 128];
    __shared__ __align__(16) unsigned char lds_vt[64 * 128];
    __shared__ __align__(16) unsigned char lds_p[4 * 16 * 128];

    const int qt = blockIdx.x, bh = blockIdx.y, tid = threadIdx.x;
    const int w = tid >> 6, lane = tid & 63, lo = lane & 15, hi = lane >> 4;
    const size_t base = (size_t)bh * S * D_DIM;
    const float* qp = Qp + base; const float* kp = Kp + base;
    const float* vp = Vp + base; float* op = Op + base;
    const int qw = qt * 64 + w * 16;

    auto swzl = [](unsigned row, unsigned colByte) {
        return (row * 128u + colByte) ^ ((row & 7u) << 4);
    };

    bf16x8 qf[2];
    {
        const float* src = qp + (size_t)(qw + lo) * D_DIM + hi * 8;
        #pragma unroll
        for (int f = 0; f < 2; ++f) {
            float4 a = *(const float4*)(src + f * 32);
            float4 b = *(const float4*)(src + f * 32 + 4);
            bf16x8 v;
            v[0] = (short)f2bf(a.x * 0.125f); v[1] = (short)f2bf(a.y * 0.125f);
            v[2] = (short)f2bf(a.z * 0.125f); v[3] = (short)f2bf(a.w * 0.125f);
            v[4] = (short)f2bf(b.x * 0.125f); v[5] = (short)f2bf(b.y * 0.125f);
            v[6] = (short)f2bf(b.z * 0.125f); v[7] = (short)f2bf(b.w * 0.125f);
            qf[f] = v;
        }
    }
    f32x4 o_acc[4]; float m_r[4], l_r[4];
    #pragma unroll
    for (int r = 0; r < 4; ++r) { m_r[r] = -__builtin_inff(); l_r[r] = 0.f; }
    #pragma unroll
    for (int dt = 0; dt < 4; ++dt) o_acc[dt] = (f32x4){0.f, 0.f, 0.f, 0.f};
    const unsigned pbase = (unsigned)w * 2048u;

    for (int t = 0; t <= qt; ++t) {
        const size_t kv0 = (size_t)t * 64;
        __syncthreads();
        #pragma unroll
        for (int jj = 0; jj < 4; ++jj) {
            int n = tid + 256 * jj;
            int r = n >> 4, c = (n & 15) << 2;
            float4 kk = *(const float4*)(kp + (kv0 + r) * D_DIM + c);
            bf16x4 kbv;
            kbv[0] = (short)f2bf(kk.x); kbv[1] = (short)f2bf(kk.y);
            kbv[2] = (short)f2bf(kk.z); kbv[3] = (short)f2bf(kk.w);
            *(bf16x4*)&lds_k[swzl((unsigned)r, (unsigned)c * 2)] = kbv;
            float4 vv = *(const float4*)(vp + (kv0 + r) * D_DIM + c);
            *(unsigned short*)&lds_vt[swzl((unsigned)(c + 0), (unsigned)r * 2)] = f2bf(vv.x);
            *(unsigned short*)&lds_vt[swzl((unsigned)(c + 1), (unsigned)r * 2)] = f2bf(vv.y);
            *(unsigned short*)&lds_vt[swzl((unsigned)(c + 2), (unsigned)r * 2)] = f2bf(vv.z);
            *(unsigned short*)&lds_vt[swzl((unsigned)(c + 3), (unsigned)r * 2)] = f2bf(vv.w);
        }
        __syncthreads();

        float sc[4][4];
        #pragma unroll
        for (int kc = 0; kc < 4; ++kc) {
            f32x4 s = (f32x4){0.f, 0.f, 0.f, 0.f};
            #pragma unroll
            for (int f = 0; f < 2; ++f) {
                bf16x8 kfv = *(const bf16x8*)&lds_k[swzl((unsigned)(kc * 16 + lo),
                                                         (unsigned)(hi * 16 + f * 64))];
                s = __builtin_amdgcn_mfma_f32_16x16x32_bf16(qf[f], kfv, s, 0, 0, 0);
            }
            #pragma unroll
            for (int r = 0; r < 4; ++r) sc[kc][r] = s[r];
        }
        if (t == qt) {
            #pragma unroll
            for (int kc = 0; kc < 4; ++kc)
                #pragma unroll
                for (int r = 0; r < 4; ++r) {
                    int qg2 = w * 16 + hi * 4 + r, kg = kc * 16 + lo;
                    if (kg > qg2) sc[kc][r] = -__builtin_inff();
                }
        }
        float scale[4];
        #pragma unroll
        for (int r = 0; r < 4; ++r) {
            float mx = fmaxf(fmaxf(sc[0][r], sc[1][r]), fmaxf(sc[2][r], sc[3][r]));
            mx = fmaxf(mx, __shfl_xor(mx, 1)); mx = fmaxf(mx, __shfl_xor(mx, 2));
            mx = fmaxf(mx, __shfl_xor(mx, 4)); mx = fmaxf(mx, __shfl_xor(mx, 8));
            float mn = fmaxf(m_r[r], mx);
            scale[r] = __expf(m_r[r] - mn); m_r[r] = mn;
            float s0 = 0.f;
            #pragma unroll
            for (int kc = 0; kc < 4; ++kc) {
                float pv = __expf(sc[kc][r] - mn); sc[kc][r] = pv; s0 += pv;
            }
            s0 += __shfl_xor(s0, 1); s0 += __shfl_xor(s0, 2);
            s0 += __shfl_xor(s0, 4); s0 += __shfl_xor(s0, 8);
            l_r[r] = l_r[r] * scale[r] + s0;
        }
        #pragma unroll
        for (int r = 0; r < 4; ++r) {
            unsigned qr = (unsigned)(hi * 4 + r);
            #pragma unroll
            for (int kc = 0; kc < 4; ++kc)
                *(unsigned short*)&lds_p[pbase + swzl(qr, (unsigned)((kc * 16 + lo) * 2))] =
                    f2bf(sc[kc][r]);
            #pragma unroll
            for (int dt = 0; dt < 4; ++dt) o_acc[dt][r] *= scale[r];
        }
        bf16x8 pa0 = *(const bf16x8*)&lds_p[pbase + swzl((unsigned)lo, (unsigned)(hi * 16))];
        bf16x8 pa1 = *(const bf16x8*)&lds_p[pbase + swzl((unsigned)lo, (unsigned)(hi * 16 + 64))];
        #pragma unroll
        for (int dt = 0; dt < 4; ++dt) {
            bf16x8 vb0 = *(const bf16x8*)&lds_vt[swzl((unsigned)(dt * 16 + lo), (unsigned)(hi * 16))];
            bf16x8 vb1 = *(const bf16x8*)&lds_vt[swzl((unsigned)(dt * 16 + lo), (unsigned)(hi * 16 + 64))];
            o_acc[dt] = __builtin_amdgcn_mfma_f32_16x16x32_bf16(pa0, vb0, o_acc[dt], 0, 0, 0);
            o_acc[dt] = __builtin_amdgcn_mfma_f32_16x16x32_bf16(pa1, vb1, o_acc[dt], 0, 0, 0);
        }
    }
    const int qrow = qw + hi * 4;
    #pragma unroll
    for (int r = 0; r < 4; ++r) {
        float inv = 1.f / l_r[r];
        #pragma unroll
        for (int dt = 0; dt < 4; ++dt)
            op[(size_t)(qrow + r) * D_DIM + dt * 16 + lo] = o_acc[dt][r] * inv;
    }
}

extern "C" void kernel_launch(void* const* d_in, const int* in_sizes, int n_in,
                              void* d_out, int out_size, void* d_ws, size_t ws_size,
                              hipStream_t stream) {
    const float* q = (const float*)d_in[0];
    const float* k = (const float*)d_in[1];
    const float* v = (const float*)d_in[2];
    float* o = (float*)d_out;

    const size_t nelem = (size_t)32 * BHD;                    // 4,194,304 per tensor
    const size_t need = 2 * nelem * sizeof(unsigned short);   // 16 MiB

    if (ws_size >= need) {
        unsigned short* kbf = (unsigned short*)d_ws;
        unsigned short* vtb = kbf + nelem;
        prep_kernel<<<dim3(32, 32), 256, 0, stream>>>(k, v, kbf, vtb);
        attn_fwd<<<dim3(16, 32), 512, 0, stream>>>(q, kbf, vtb, o);
    } else {
        attn_fwd_fb<<<dim3(32, 32), 256, 0, stream>>>(q, k, v, o, SEQ);
    }
}